// Round 8
// baseline (427.207 us; speedup 1.0000x reference)
//
#include <hip/hip_runtime.h>
#include <hip/hip_bf16.h>
#include <cstdint>

// SimVQ forward: b=8, n=1024 (R=8192 rows), dim=512, codes C=4096.
// Outputs flat f32: rotated [8192*512], indices-as-float [8192], loss [1].
//
// Round-8: 1-term FP16 score (K=512) + CERTIFICATE margins + r6-bit refine.
//   f16 score err: Hoeffding P(|err| > 0.0305) < 1e-17/pair.
//   MARGIN  = 8e-2 > 2*e_max  -> every near-tie row deterministically flagged;
//   unflagged wrong argmin needs err-diff > 0.08 (~exp(-69), impossible).
//   TILE_MARGIN = 8e-2 -> true-best tile always considered by refine.
// Everything deciding final answers (cb f32 GEMM, rowsumsq, refine) is
// bit-identical to the round-6 PASSING build.

#define R_ROWS 8192
#define DIM    512
#define NCODES 4096
#define BK     16
#define MARGIN      8.0e-2f
#define TILE_MARGIN 8.0e-2f

typedef __attribute__((ext_vector_type(8))) _Float16 f16x8;
typedef __attribute__((ext_vector_type(4))) float f32x4;
typedef __attribute__((ext_vector_type(8))) unsigned short ushort8;

__device__ __forceinline__ void gload_lds16(const void* g, void* l) {
    __builtin_amdgcn_global_load_lds(
        (const __attribute__((address_space(1))) void*)g,
        (__attribute__((address_space(3))) void*)l, 16, 0, 0);
}

// ---------------- generic f32 NT GEMM (cb + fallback) -----------------------
template<int BM, int BN, int TM, int TN, bool ARGMIN>
__launch_bounds__(256)
__global__ void gemm_nt(const float* __restrict__ A, const float* __restrict__ Bm,
                        float* __restrict__ Cout,
                        const float* __restrict__ rowAdd, const float* __restrict__ colAdd,
                        float* __restrict__ pVal, int* __restrict__ pIdx,
                        int M, int N, int K) {
    constexpr int THREADS = (BM / TM) * (BN / TN);
    constexpr int PAD = 4;
    __shared__ float As[BK][BM + PAD];
    __shared__ float Bs[BK][BN + PAD];

    const int tid = threadIdx.x;
    const int tx = tid % (BN / TN);
    const int ty = tid / (BN / TN);
    const int rowBase = blockIdx.y * BM;
    const int colBase = blockIdx.x * BN;

    float acc[TM][TN];
#pragma unroll
    for (int i = 0; i < TM; i++)
#pragma unroll
        for (int j = 0; j < TN; j++) acc[i][j] = 0.f;

    constexpr int A_F4 = BM * BK / 4;
    constexpr int B_F4 = BN * BK / 4;
    const int nK = K / BK;

    for (int kt = 0; kt < nK; ++kt) {
        const int k0 = kt * BK;
#pragma unroll
        for (int f = 0; f < A_F4 / THREADS; ++f) {
            int e = tid + f * THREADS;
            int row = e >> 2;
            int kq = e & 3;
            float4 v = *reinterpret_cast<const float4*>(
                &A[(size_t)(rowBase + row) * K + k0 + kq * 4]);
            As[kq * 4 + 0][row] = v.x; As[kq * 4 + 1][row] = v.y;
            As[kq * 4 + 2][row] = v.z; As[kq * 4 + 3][row] = v.w;
        }
#pragma unroll
        for (int f = 0; f < B_F4 / THREADS; ++f) {
            int e = tid + f * THREADS;
            int row = e >> 2;
            int kq = e & 3;
            float4 v = *reinterpret_cast<const float4*>(
                &Bm[(size_t)(colBase + row) * K + k0 + kq * 4]);
            Bs[kq * 4 + 0][row] = v.x; Bs[kq * 4 + 1][row] = v.y;
            Bs[kq * 4 + 2][row] = v.z; Bs[kq * 4 + 3][row] = v.w;
        }
        __syncthreads();

#pragma unroll
        for (int k = 0; k < BK; k++) {
            float a[TM], b[TN];
#pragma unroll
            for (int i4 = 0; i4 < TM / 4; i4++) {
                float4 v = *reinterpret_cast<const float4*>(&As[k][ty * TM + i4 * 4]);
                a[i4 * 4 + 0] = v.x; a[i4 * 4 + 1] = v.y;
                a[i4 * 4 + 2] = v.z; a[i4 * 4 + 3] = v.w;
            }
#pragma unroll
            for (int j4 = 0; j4 < TN / 4; j4++) {
                float4 v = *reinterpret_cast<const float4*>(&Bs[k][tx * TN + j4 * 4]);
                b[j4 * 4 + 0] = v.x; b[j4 * 4 + 1] = v.y;
                b[j4 * 4 + 2] = v.z; b[j4 * 4 + 3] = v.w;
            }
#pragma unroll
            for (int i = 0; i < TM; i++)
#pragma unroll
                for (int j = 0; j < TN; j++) acc[i][j] = fmaf(a[i], b[j], acc[i][j]);
        }
        __syncthreads();
    }

    if constexpr (!ARGMIN) {
#pragma unroll
        for (int i = 0; i < TM; i++) {
#pragma unroll
            for (int j4 = 0; j4 < TN / 4; j4++) {
                float4 v = make_float4(acc[i][j4 * 4 + 0], acc[i][j4 * 4 + 1],
                                       acc[i][j4 * 4 + 2], acc[i][j4 * 4 + 3]);
                *reinterpret_cast<float4*>(
                    &Cout[(size_t)(rowBase + ty * TM + i) * N + colBase + tx * TN + j4 * 4]) = v;
            }
        }
    } else {
        constexpr int TX = BN / TN;
        __shared__ float rV[BM][TX + 1];
        __shared__ int   rI[BM][TX + 1];
        float xn[TM];
#pragma unroll
        for (int i = 0; i < TM; i++) xn[i] = rowAdd[rowBase + ty * TM + i];
        float cn[TN];
#pragma unroll
        for (int j = 0; j < TN; j++) cn[j] = colAdd[colBase + tx * TN + j];

#pragma unroll
        for (int i = 0; i < TM; i++) {
            float bv = 3.402823466e38f; int bi = 0;
#pragma unroll
            for (int j = 0; j < TN; j++) {
                float s = xn[i] + cn[j] - 2.f * acc[i][j];
                if (s < bv) { bv = s; bi = colBase + tx * TN + j; }
            }
            rV[ty * TM + i][tx] = bv;
            rI[ty * TM + i][tx] = bi;
        }
        __syncthreads();
        if (tid < BM) {
            float bv = 3.402823466e38f; int bi = 0;
#pragma unroll
            for (int t = 0; t < TX; t++) {
                float v = rV[tid][t];
                if (v < bv) { bv = v; bi = rI[tid][t]; }
            }
            int gr = rowBase + tid;
            pVal[(size_t)gr * gridDim.x + blockIdx.x] = bv;
            pIdx[(size_t)gr * gridDim.x + blockIdx.x] = bi;
        }
    }
}

// ------------- per-row sum of squares (r6 bits) -----------------------------
__global__ void rowsumsq(const float* __restrict__ src, float* __restrict__ dst, int nRows) {
    int gw = (blockIdx.x * blockDim.x + threadIdx.x) >> 6;
    int lane = threadIdx.x & 63;
    if (gw >= nRows) return;
    const float4* s4 = reinterpret_cast<const float4*>(src + (size_t)gw * DIM);
    float4 a = s4[lane];
    float4 b = s4[lane + 64];
    float s = a.x * a.x + a.y * a.y + a.z * a.z + a.w * a.w
            + b.x * b.x + b.y * b.y + b.z * b.z + b.w * b.w;
#pragma unroll
    for (int o = 32; o; o >>= 1) s += __shfl_xor(s, o);
    if (lane == 0) dst[gw] = s;
}

// ------------- f32 -> f16 cast (8 elems / thread) ---------------------------
__global__ void cast_f16(const float* __restrict__ src, ushort* __restrict__ dst, int n8) {
    int t = blockIdx.x * blockDim.x + threadIdx.x;
    if (t >= n8) return;
    float4 a = reinterpret_cast<const float4*>(src)[(size_t)t * 2];
    float4 b = reinterpret_cast<const float4*>(src)[(size_t)t * 2 + 1];
    float v[8] = {a.x, a.y, a.z, a.w, b.x, b.y, b.z, b.w};
    ushort8 h;
#pragma unroll
    for (int e = 0; e < 8; ++e) {
        _Float16 hv = (_Float16)v[e];
        h[e] = *reinterpret_cast<unsigned short*>(&hv);
    }
    reinterpret_cast<ushort8*>(dst)[t] = h;
}

// ================= 256x256 8-phase MFMA f16 score GEMM (1-term) ==============
// [8192 x 512]f16 * [4096 x 512]f16^T. 8 K-tiles of 64. 8 waves (2M x 4N).
// LDS 128 KiB: 2 buf x (A,B) x 2 KH x 16 KB; 64B rows, g-XOR bank swizzle
// (r5-verified). Counted vmcnt(6) once per K-tile (r6-verified ledger,
// re-verified for NT_K=8 incl. wrap staging at kt=6,7).

#define NT_K 8
#define LDSOFF(BUF, ISB, KH) ((BUF) * 65536 + (ISB) * 32768 + (KH) * 16384)

__device__ __forceinline__ f16x8 read_frag(const char* half_base, int row, int g) {
    int gp = g ^ ((row >> 1) & 3);
    return *reinterpret_cast<const f16x8*>(half_base + row * 64 + gp * 16);
}

__device__ __forceinline__ void stage_half(const ushort* __restrict__ src, int rowBase,
                                           int segElem, char* ldsBase, int tid) {
#pragma unroll
    for (int i = 0; i < 2; ++i) {
        int o = i * 8192 + tid * 16;
        int row = o >> 6;
        int gp  = (o >> 4) & 3;
        int g   = gp ^ ((row >> 1) & 3);
        const char* gsrc = (const char*)src + (size_t)(rowBase + row) * 1024
                         + (size_t)segElem * 2 + g * 16;
        gload_lds16(gsrc, ldsBase + i * 8192 + (tid >> 6) * 1024);
    }
}

#define STAGE(STKT, STISB, STKH) do {                                          \
    int sk_ = (STKT) >= NT_K ? (STKT) - NT_K : (STKT);                         \
    int se_ = (sk_ << 6) + (STKH) * 32;                                        \
    const ushort* sp_ = (STISB) ? ch : xh;                                     \
    int rb_ = (STISB) ? colBase : rowBase;                                     \
    stage_half(sp_, rb_, se_, ldsc + LDSOFF((sk_ & 1), (STISB), (STKH)), tid); \
} while (0)

#define ENDP() do {                                                            \
    __builtin_amdgcn_s_barrier();                                              \
} while (0)
#define ENDV6() do {                                                           \
    asm volatile("s_waitcnt vmcnt(6)");                                        \
    __builtin_amdgcn_sched_barrier(0);                                         \
    __builtin_amdgcn_s_barrier();                                              \
} while (0)

#define PHASE_A(BUF, KS, STKT, STISB, STKH) do {                               \
    __builtin_amdgcn_sched_barrier(0);                                         \
    _Pragma("unroll")                                                          \
    for (int m_ = 0; m_ < 4; ++m_)                                             \
        af_[m_] = read_frag(ldsc + LDSOFF((BUF), 0, (KS)),                     \
                            wr * 128 + m_ * 16 + c15, g);                      \
    _Pragma("unroll")                                                          \
    for (int n_ = 0; n_ < 4; ++n_)                                             \
        bf_[n_] = read_frag(ldsc + LDSOFF((BUF), 1, (KS)),                     \
                            wc * 64 + n_ * 16 + c15, g);                       \
    STAGE((STKT), (STISB), (STKH));                                            \
    __builtin_amdgcn_sched_barrier(0);                                         \
    __builtin_amdgcn_s_barrier();                                              \
    asm volatile("s_waitcnt lgkmcnt(0)");                                      \
    __builtin_amdgcn_sched_barrier(0);                                         \
    __builtin_amdgcn_s_setprio(1);                                             \
    _Pragma("unroll")                                                          \
    for (int m_ = 0; m_ < 4; ++m_)                                             \
        _Pragma("unroll")                                                      \
        for (int n_ = 0; n_ < 4; ++n_)                                         \
            acc[m_][n_] = __builtin_amdgcn_mfma_f32_16x16x32_f16(              \
                af_[m_], bf_[n_], acc[m_][n_], 0, 0, 0);                       \
    __builtin_amdgcn_s_setprio(0);                                             \
    __builtin_amdgcn_sched_barrier(0);                                         \
} while (0)

#define PHASE_B(BUF, KS, STKT, STISB, STKH) do {                               \
    __builtin_amdgcn_sched_barrier(0);                                         \
    _Pragma("unroll")                                                          \
    for (int m_ = 0; m_ < 4; ++m_)                                             \
        af_[m_] = read_frag(ldsc + LDSOFF((BUF), 0, (KS)),                     \
                            wr * 128 + 64 + m_ * 16 + c15, g);                 \
    STAGE((STKT), (STISB), (STKH));                                            \
    __builtin_amdgcn_sched_barrier(0);                                         \
    __builtin_amdgcn_s_barrier();                                              \
    asm volatile("s_waitcnt lgkmcnt(0)");                                      \
    __builtin_amdgcn_sched_barrier(0);                                         \
    __builtin_amdgcn_s_setprio(1);                                             \
    _Pragma("unroll")                                                          \
    for (int m_ = 0; m_ < 4; ++m_)                                             \
        _Pragma("unroll")                                                      \
        for (int n_ = 0; n_ < 4; ++n_)                                         \
            acc[4 + m_][n_] = __builtin_amdgcn_mfma_f32_16x16x32_f16(          \
                af_[m_], bf_[n_], acc[4 + m_][n_], 0, 0, 0);                   \
    __builtin_amdgcn_s_setprio(0);                                             \
    __builtin_amdgcn_sched_barrier(0);                                         \
} while (0)

__launch_bounds__(512, 2)
__global__ void score_mfma8(const ushort* __restrict__ xh, const ushort* __restrict__ ch,
                            const float* __restrict__ xn2, const float* __restrict__ cn2,
                            float* __restrict__ pV1, float* __restrict__ pV2,
                            int* __restrict__ pI1) {
    __shared__ __align__(16) ushort LDSarr[65536];   // 128 KiB
    char* ldsc = (char*)LDSarr;

    int bid = blockIdx.x;                    // 512 blocks, 512 % 8 == 0
    int swz = (bid & 7) * 64 + (bid >> 3);   // XCD-aware
    int tileN = swz & 15;                    // 16 N tiles (4096/256)
    int tileM = swz >> 4;                    // 32 M tiles (8192/256)
    int rowBase = tileM * 256, colBase = tileN * 256;

    int tid = threadIdx.x, lane = tid & 63, w = tid >> 6;
    int wr = w >> 2, wc = w & 3;             // 2M x 4N wave grid
    int g = lane >> 4, c15 = lane & 15;

    f32x4 acc[8][4];
#pragma unroll
    for (int m = 0; m < 8; m++)
#pragma unroll
        for (int n = 0; n < 4; n++) acc[m][n] = (f32x4){0.f, 0.f, 0.f, 0.f};

    f16x8 af_[4], bf_[4];

    // prologue: T0 x4 + [B1.KH0, A1.KH0, B1.KH1] = 14 thread-instrs
    STAGE(0, 0, 0); STAGE(0, 1, 0); STAGE(0, 0, 1); STAGE(0, 1, 1);
    STAGE(1, 1, 0); STAGE(1, 0, 0); STAGE(1, 1, 1);
    __builtin_amdgcn_sched_barrier(0);
    asm volatile("s_waitcnt vmcnt(6)");      // T0 fully landed; 3 halves pending
    __builtin_amdgcn_sched_barrier(0);
    __builtin_amdgcn_s_barrier();

    for (int kt = 0; kt < NT_K; ++kt) {
        int buf = kt & 1;
        PHASE_A(buf, 0, kt + 1, 0, 1); ENDP();   // S1: A(kt+1).KH1
        PHASE_B(buf, 0, kt + 2, 1, 0); ENDP();   // S2: B(kt+2).KH0
        PHASE_A(buf, 1, kt + 2, 0, 0); ENDP();   // S3: A(kt+2).KH0
        PHASE_B(buf, 1, kt + 2, 1, 1); ENDV6();  // S4: B(kt+2).KH1 + vmcnt(6)
    }

    __syncthreads();   // full drain; LDS reused for reduction below

    // epilogue: score = xn2[row] + cn2[col] - 2*dot ; per-row (min1, idx1, min2)
    float* rv1 = (float*)ldsc;            // [256][4]
    float* rv2 = rv1 + 1024;              // [256][4]
    int*   ri1 = (int*)(rv1 + 2048);      // [256][4]

    float cnv[4];
#pragma unroll
    for (int n = 0; n < 4; ++n) cnv[n] = cn2[colBase + wc * 64 + n * 16 + c15];

#pragma unroll
    for (int m = 0; m < 8; ++m) {
#pragma unroll
        for (int j = 0; j < 4; ++j) {
            int rl = wr * 128 + m * 16 + g * 4 + j;
            float xn = xn2[rowBase + rl];
            float v1 = 3.402823466e38f, v2 = 3.402823466e38f; int i1 = 0x7fffffff;
#pragma unroll
            for (int n = 0; n < 4; ++n) {
                float s = xn + cnv[n] - 2.f * acc[m][n][j];
                int ci = colBase + wc * 64 + n * 16 + c15;
                if (s < v1 || (s == v1 && ci < i1)) { v2 = v1; v1 = s; i1 = ci; }
                else if (s < v2) v2 = s;
            }
#pragma unroll
            for (int off = 1; off < 16; off <<= 1) {
                float ov1 = __shfl_xor(v1, off);
                int   oi1 = __shfl_xor(i1, off);
                float ov2 = __shfl_xor(v2, off);
                if (ov1 < v1 || (ov1 == v1 && oi1 < i1)) {
                    v2 = fminf(v1, ov2); v1 = ov1; i1 = oi1;
                } else {
                    v2 = fminf(v2, ov1);
                }
            }
            if (c15 == 0) {
                rv1[rl * 4 + wc] = v1; rv2[rl * 4 + wc] = v2; ri1[rl * 4 + wc] = i1;
            }
        }
    }
    __syncthreads();
    if (tid < 256) {
        float v1 = 3.402823466e38f, v2 = 3.402823466e38f; int i1 = 0x7fffffff;
#pragma unroll
        for (int t = 0; t < 4; ++t) {
            float a1 = rv1[tid * 4 + t], a2 = rv2[tid * 4 + t];
            int   ai = ri1[tid * 4 + t];
            if (a1 < v1 || (a1 == v1 && ai < i1)) { v2 = fminf(v1, a2); v1 = a1; i1 = ai; }
            else { v2 = fminf(v2, a1); }
        }
        size_t o = (size_t)(rowBase + tid) * 16 + tileN;
        pV1[o] = v1; pV2[o] = v2; pI1[o] = i1;
    }
}

// ------------- combine per-tile partials -> idx + near-tie flag -------------
__global__ void combine_flag(const float* __restrict__ pV1, const float* __restrict__ pV2,
                             const int* __restrict__ pI1,
                             int* __restrict__ idx, float* __restrict__ idxF,
                             int* __restrict__ flag, float* __restrict__ vminOut) {
    int r = blockIdx.x * blockDim.x + threadIdx.x;
    if (r >= R_ROWS) return;
    float v1 = 3.402823466e38f, v2 = 3.402823466e38f; int i1 = 0x7fffffff;
    for (int t = 0; t < 16; ++t) {
        float a1 = pV1[(size_t)r * 16 + t];
        float a2 = pV2[(size_t)r * 16 + t];
        int   ai = pI1[(size_t)r * 16 + t];
        if (a1 < v1 || (a1 == v1 && ai < i1)) { v2 = fminf(v1, a2); v1 = a1; i1 = ai; }
        else { v2 = fminf(v2, a1); }
    }
    idx[r] = i1;
    idxF[r] = (float)i1;
    vminOut[r] = v1;
    flag[r] = (v2 - v1 < MARGIN) ? 1 : 0;
}

// ------------- exact f32 re-score of near-tie rows (r6 bits) ----------------
__launch_bounds__(256)
__global__ void refine_rows(const float* __restrict__ x, const float* __restrict__ cb,
                            const float* __restrict__ xn2, const float* __restrict__ cn2,
                            const float* __restrict__ pV1, const float* __restrict__ vmin,
                            const int* __restrict__ flag,
                            int* __restrict__ idx, float* __restrict__ idxF) {
    int r = blockIdx.x;
    if (flag[r] == 0) return;

    __shared__ float xs[DIM];
    __shared__ float sv[256];
    __shared__ int   si[256];
    for (int i = threadIdx.x; i < DIM; i += 256) xs[i] = x[(size_t)r * DIM + i];
    __syncthreads();

    float xn = xn2[r];
    float thr = vmin[r] + TILE_MARGIN;
    float v1 = 3.402823466e38f; int i1 = 0x7fffffff;

    for (int t = 0; t < 16; ++t) {
        if (pV1[(size_t)r * 16 + t] > thr) continue;
        int c = t * 256 + threadIdx.x;
        const float4* cr = reinterpret_cast<const float4*>(cb + (size_t)c * DIM);
        float dot = 0.f;
#pragma unroll 8
        for (int k = 0; k < DIM / 4; ++k) {
            float4 cv = cr[k];
            dot = fmaf(xs[k * 4 + 0], cv.x, dot);
            dot = fmaf(xs[k * 4 + 1], cv.y, dot);
            dot = fmaf(xs[k * 4 + 2], cv.z, dot);
            dot = fmaf(xs[k * 4 + 3], cv.w, dot);
        }
        float s = xn + cn2[c] - 2.f * dot;
        if (s < v1 || (s == v1 && c < i1)) { v1 = s; i1 = c; }
    }
    sv[threadIdx.x] = v1; si[threadIdx.x] = i1;
    __syncthreads();
    for (int o = 128; o; o >>= 1) {
        if (threadIdx.x < o) {
            float ov = sv[threadIdx.x + o]; int oi = si[threadIdx.x + o];
            if (ov < sv[threadIdx.x] || (ov == sv[threadIdx.x] && oi < si[threadIdx.x])) {
                sv[threadIdx.x] = ov; si[threadIdx.x] = oi;
            }
        }
        __syncthreads();
    }
    if (threadIdx.x == 0) { idx[r] = si[0]; idxF[r] = (float)si[0]; }
}

// ------------- combine per-tile argmin partials (fallback path) -------------
__global__ void argmin_combine(const float* __restrict__ pVal, const int* __restrict__ pIdx,
                               int* __restrict__ idxOut, float* __restrict__ idxFloatOut,
                               int nTiles) {
    int r = blockIdx.x * blockDim.x + threadIdx.x;
    if (r >= R_ROWS) return;
    float bv = 3.402823466e38f; int bi = 0;
    for (int t = 0; t < nTiles; t++) {
        float v = pVal[(size_t)r * nTiles + t];
        if (v < bv) { bv = v; bi = pIdx[(size_t)r * nTiles + t]; }
    }
    idxOut[r] = bi;
    idxFloatOut[r] = (float)bi;
}

// ------------- rotation trick, one wave per row -----------------------------
__global__ void rotate_rows(const float* __restrict__ x, const float* __restrict__ cb,
                            const int* __restrict__ idx, float* __restrict__ out,
                            float* __restrict__ lossPartial) {
    int gw = (blockIdx.x * blockDim.x + threadIdx.x) >> 6;
    int lane = threadIdx.x & 63;
    if (gw >= R_ROWS) return;

    const float4* x4 = reinterpret_cast<const float4*>(x + (size_t)gw * DIM);
    float4 xa = x4[lane], xb = x4[lane + 64];
    int ci = idx[gw];
    const float4* q4 = reinterpret_cast<const float4*>(cb + (size_t)ci * DIM);
    float4 qa = q4[lane], qb = q4[lane + 64];

    float xe[8] = {xa.x, xa.y, xa.z, xa.w, xb.x, xb.y, xb.z, xb.w};
    float qe[8] = {qa.x, qa.y, qa.z, qa.w, qb.x, qb.y, qb.z, qb.w};

    auto wsum = [&](float v) {
#pragma unroll
        for (int o = 32; o; o >>= 1) v += __shfl_xor(v, o);
        return v;
    };

    float lx = 0.f, lq = 0.f, ld = 0.f;
#pragma unroll
    for (int e = 0; e < 8; e++) {
        lx += xe[e] * xe[e];
        lq += qe[e] * qe[e];
        float d = xe[e] - qe[e];
        ld += d * d;
    }
    float sx2 = wsum(lx);
    float sq2 = wsum(lq);
    float lp  = wsum(ld);

    float nx = sqrtf(sx2), nq = sqrtf(sq2);
    float inx = 1.f / fmaxf(nx, 1e-6f);
    float inq = 1.f / fmaxf(nq, 1e-6f);

    float ue[8], qh[8], we[8];
    float lw = 0.f;
#pragma unroll
    for (int e = 0; e < 8; e++) {
        ue[e] = xe[e] * inx;
        qh[e] = qe[e] * inq;
        we[e] = ue[e] + qh[e];
        lw += we[e] * we[e];
    }
    float sw2 = wsum(lw);
    float inw = 1.f / fmaxf(sqrtf(sw2), 1e-6f);

    float lew = 0.f, leu = 0.f;
#pragma unroll
    for (int e = 0; e < 8; e++) {
        we[e] *= inw;
        lew += xe[e] * we[e];
        leu += xe[e] * ue[e];
    }
    float ew = wsum(lew);
    float eu = wsum(leu);

    float scale = nq / fmaxf(nx, 1e-6f);
    float oe[8];
#pragma unroll
    for (int e = 0; e < 8; e++)
        oe[e] = (xe[e] - 2.f * ew * we[e] + 2.f * eu * qh[e]) * scale;

    float4* o4 = reinterpret_cast<float4*>(out + (size_t)gw * DIM);
    o4[lane]      = make_float4(oe[0], oe[1], oe[2], oe[3]);
    o4[lane + 64] = make_float4(oe[4], oe[5], oe[6], oe[7]);

    if (lane == 0) lossPartial[gw] = lp;
}

// ------------- final loss reduction -----------------------------------------
__global__ void loss_reduce(const float* __restrict__ lp, float* __restrict__ outScalar) {
    __shared__ float red[256];
    float s = 0.f;
    for (int i = threadIdx.x; i < R_ROWS; i += 256) s += lp[i];
    red[threadIdx.x] = s;
    __syncthreads();
    for (int o = 128; o; o >>= 1) {
        if (threadIdx.x < o) red[threadIdx.x] += red[threadIdx.x + o];
        __syncthreads();
    }
    if (threadIdx.x == 0)
        outScalar[0] = 1.25f * red[0] / (float)(R_ROWS * DIM);
}

extern "C" void kernel_launch(void* const* d_in, const int* in_sizes, int n_in,
                              void* d_out, int out_size, void* d_ws, size_t ws_size,
                              hipStream_t stream) {
    const float* x      = (const float*)d_in[0];   // [8192, 512]
    const float* frozen = (const float*)d_in[1];   // [4096, 512]
    const float* weight = (const float*)d_in[2];   // [512, 512]
    float* out = (float*)d_out;

    // ---- workspace layout (MFMA path), ~23 MB ----
    char* p = (char*)d_ws;
    float* cb  = (float*)p;            p += (size_t)NCODES * DIM * 4;
    ushort* xh = (ushort*)p;           p += (size_t)R_ROWS * DIM * 2;
    ushort* ch = (ushort*)p;           p += (size_t)NCODES * DIM * 2;
    float* cn2 = (float*)p;            p += NCODES * 4;
    float* xn2 = (float*)p;            p += R_ROWS * 4;
    float* pV1 = (float*)p;            p += (size_t)R_ROWS * 16 * 4;
    float* pV2 = (float*)p;            p += (size_t)R_ROWS * 16 * 4;
    int*   pI1 = (int*)p;              p += (size_t)R_ROWS * 16 * 4;
    int*   idx = (int*)p;              p += R_ROWS * 4;
    int*   flg = (int*)p;              p += R_ROWS * 4;
    float* vmn = (float*)p;            p += R_ROWS * 4;
    float* lp  = (float*)p;            p += R_ROWS * 4;
    size_t need = (size_t)(p - (char*)d_ws);

    if (ws_size >= need) {
        // 1. codebook = frozen @ W^T : f32 GEMM (round-6 bits)
        dim3 g1(DIM / 64, NCODES / 64);
        gemm_nt<64, 64, 4, 4, false><<<g1, 256, 0, stream>>>(
            frozen, weight, cb, nullptr, nullptr, nullptr, nullptr, NCODES, DIM, DIM);

        // 2. exact row norms (round-6 bits)
        rowsumsq<<<NCODES / 4, 256, 0, stream>>>(cb, cn2, NCODES);
        rowsumsq<<<R_ROWS / 4, 256, 0, stream>>>(x, xn2, R_ROWS);

        // 3. f16 casts
        cast_f16<<<(R_ROWS * DIM / 8) / 256, 256, 0, stream>>>(x, xh, R_ROWS * DIM / 8);
        cast_f16<<<(NCODES * DIM / 8) / 256, 256, 0, stream>>>(cb, ch, NCODES * DIM / 8);

        // 4. 1-term f16 MFMA score GEMM + per-tile (min1, idx1, min2)
        score_mfma8<<<(R_ROWS / 256) * (NCODES / 256), 512, 0, stream>>>(
            xh, ch, xn2, cn2, pV1, pV2, pI1);

        // 5. combine + near-tie flag (MARGIN certificate-grade)
        combine_flag<<<R_ROWS / 256, 256, 0, stream>>>(
            pV1, pV2, pI1, idx, out + (size_t)R_ROWS * DIM, flg, vmn);

        // 6. exact f32 re-score of flagged rows (round-6 bits)
        refine_rows<<<R_ROWS, 256, 0, stream>>>(
            x, cb, xn2, cn2, pV1, vmn, flg, idx, out + (size_t)R_ROWS * DIM);

        // 7. rotation trick + loss
        rotate_rows<<<R_ROWS / 4, 256, 0, stream>>>(x, cb, idx, out, lp);
        loss_reduce<<<1, 256, 0, stream>>>(lp, out + ((size_t)R_ROWS * DIM + R_ROWS));
    } else {
        // fallback: proven f32 path (~11 MB)
        float* fcn2 = (float*)((char*)d_ws + (size_t)NCODES * DIM * 4);
        float* fxn2 = fcn2 + NCODES;
        float* fpV = fxn2 + R_ROWS;
        int*   fpI = (int*)(fpV + (size_t)R_ROWS * 32);
        int*   fidx = (int*)(fpI + (size_t)R_ROWS * 32);
        float* flp = (float*)(fidx + R_ROWS);
        dim3 g1(DIM / 64, NCODES / 64);
        gemm_nt<64, 64, 4, 4, false><<<g1, 256, 0, stream>>>(
            frozen, weight, cb, nullptr, nullptr, nullptr, nullptr, NCODES, DIM, DIM);
        rowsumsq<<<NCODES / 4, 256, 0, stream>>>(cb, fcn2, NCODES);
        rowsumsq<<<R_ROWS / 4, 256, 0, stream>>>(x, fxn2, R_ROWS);
        dim3 g2(NCODES / 128, R_ROWS / 128);
        gemm_nt<128, 128, 8, 8, true><<<g2, 256, 0, stream>>>(
            x, cb, nullptr, fxn2, fcn2, fpV, fpI, R_ROWS, NCODES, DIM);
        argmin_combine<<<R_ROWS / 256, 256, 0, stream>>>(
            fpV, fpI, fidx, out + (size_t)R_ROWS * DIM, NCODES / 128);
        rotate_rows<<<R_ROWS / 4, 256, 0, stream>>>(x, cb, fidx, out, flp);
        loss_reduce<<<1, 256, 0, stream>>>(flp, out + ((size_t)R_ROWS * DIM + R_ROWS));
    }
}

// Round 9
// 258.985 us; speedup vs baseline: 1.6495x; 1.6495x over previous
//
#include <hip/hip_runtime.h>
#include <hip/hip_bf16.h>
#include <cstdint>

// SimVQ forward: b=8, n=1024 (R=8192 rows), dim=512, codes C=4096.
// Outputs flat f32: rotated [8192*512], indices-as-float [8192], loss [1].
//
// Round-9: 1-term FP16 score (K=512, r8-verified) + right-sized margins +
// wave-cooperative coalesced refine.
//   f16 score-error-diff sigma ~5.7e-4; MARGIN=1.5e-2 (~26 sigma),
//   TILE_MARGIN=1.8e-2 (>= 2*e_max certificate). Flags ~12-15% of rows.
// cb f32 GEMM / rowsumsq bits unchanged from r6/r8 PASSING builds (r7 showed
// perturbing cb flips near-tie refine results vs numpy).

#define R_ROWS 8192
#define DIM    512
#define NCODES 4096
#define BK     16
#define MARGIN      1.5e-2f
#define TILE_MARGIN 1.8e-2f

typedef __attribute__((ext_vector_type(8))) _Float16 f16x8;
typedef __attribute__((ext_vector_type(4))) float f32x4;
typedef __attribute__((ext_vector_type(8))) unsigned short ushort8;

__device__ __forceinline__ void gload_lds16(const void* g, void* l) {
    __builtin_amdgcn_global_load_lds(
        (const __attribute__((address_space(1))) void*)g,
        (__attribute__((address_space(3))) void*)l, 16, 0, 0);
}

// ---------------- generic f32 NT GEMM (cb + fallback) -----------------------
template<int BM, int BN, int TM, int TN, bool ARGMIN>
__launch_bounds__(256)
__global__ void gemm_nt(const float* __restrict__ A, const float* __restrict__ Bm,
                        float* __restrict__ Cout,
                        const float* __restrict__ rowAdd, const float* __restrict__ colAdd,
                        float* __restrict__ pVal, int* __restrict__ pIdx,
                        int M, int N, int K) {
    constexpr int THREADS = (BM / TM) * (BN / TN);
    constexpr int PAD = 4;
    __shared__ float As[BK][BM + PAD];
    __shared__ float Bs[BK][BN + PAD];

    const int tid = threadIdx.x;
    const int tx = tid % (BN / TN);
    const int ty = tid / (BN / TN);
    const int rowBase = blockIdx.y * BM;
    const int colBase = blockIdx.x * BN;

    float acc[TM][TN];
#pragma unroll
    for (int i = 0; i < TM; i++)
#pragma unroll
        for (int j = 0; j < TN; j++) acc[i][j] = 0.f;

    constexpr int A_F4 = BM * BK / 4;
    constexpr int B_F4 = BN * BK / 4;
    const int nK = K / BK;

    for (int kt = 0; kt < nK; ++kt) {
        const int k0 = kt * BK;
#pragma unroll
        for (int f = 0; f < A_F4 / THREADS; ++f) {
            int e = tid + f * THREADS;
            int row = e >> 2;
            int kq = e & 3;
            float4 v = *reinterpret_cast<const float4*>(
                &A[(size_t)(rowBase + row) * K + k0 + kq * 4]);
            As[kq * 4 + 0][row] = v.x; As[kq * 4 + 1][row] = v.y;
            As[kq * 4 + 2][row] = v.z; As[kq * 4 + 3][row] = v.w;
        }
#pragma unroll
        for (int f = 0; f < B_F4 / THREADS; ++f) {
            int e = tid + f * THREADS;
            int row = e >> 2;
            int kq = e & 3;
            float4 v = *reinterpret_cast<const float4*>(
                &Bm[(size_t)(colBase + row) * K + k0 + kq * 4]);
            Bs[kq * 4 + 0][row] = v.x; Bs[kq * 4 + 1][row] = v.y;
            Bs[kq * 4 + 2][row] = v.z; Bs[kq * 4 + 3][row] = v.w;
        }
        __syncthreads();

#pragma unroll
        for (int k = 0; k < BK; k++) {
            float a[TM], b[TN];
#pragma unroll
            for (int i4 = 0; i4 < TM / 4; i4++) {
                float4 v = *reinterpret_cast<const float4*>(&As[k][ty * TM + i4 * 4]);
                a[i4 * 4 + 0] = v.x; a[i4 * 4 + 1] = v.y;
                a[i4 * 4 + 2] = v.z; a[i4 * 4 + 3] = v.w;
            }
#pragma unroll
            for (int j4 = 0; j4 < TN / 4; j4++) {
                float4 v = *reinterpret_cast<const float4*>(&Bs[k][tx * TN + j4 * 4]);
                b[j4 * 4 + 0] = v.x; b[j4 * 4 + 1] = v.y;
                b[j4 * 4 + 2] = v.z; b[j4 * 4 + 3] = v.w;
            }
#pragma unroll
            for (int i = 0; i < TM; i++)
#pragma unroll
                for (int j = 0; j < TN; j++) acc[i][j] = fmaf(a[i], b[j], acc[i][j]);
        }
        __syncthreads();
    }

    if constexpr (!ARGMIN) {
#pragma unroll
        for (int i = 0; i < TM; i++) {
#pragma unroll
            for (int j4 = 0; j4 < TN / 4; j4++) {
                float4 v = make_float4(acc[i][j4 * 4 + 0], acc[i][j4 * 4 + 1],
                                       acc[i][j4 * 4 + 2], acc[i][j4 * 4 + 3]);
                *reinterpret_cast<float4*>(
                    &Cout[(size_t)(rowBase + ty * TM + i) * N + colBase + tx * TN + j4 * 4]) = v;
            }
        }
    } else {
        constexpr int TX = BN / TN;
        __shared__ float rV[BM][TX + 1];
        __shared__ int   rI[BM][TX + 1];
        float xn[TM];
#pragma unroll
        for (int i = 0; i < TM; i++) xn[i] = rowAdd[rowBase + ty * TM + i];
        float cn[TN];
#pragma unroll
        for (int j = 0; j < TN; j++) cn[j] = colAdd[colBase + tx * TN + j];

#pragma unroll
        for (int i = 0; i < TM; i++) {
            float bv = 3.402823466e38f; int bi = 0;
#pragma unroll
            for (int j = 0; j < TN; j++) {
                float s = xn[i] + cn[j] - 2.f * acc[i][j];
                if (s < bv) { bv = s; bi = colBase + tx * TN + j; }
            }
            rV[ty * TM + i][tx] = bv;
            rI[ty * TM + i][tx] = bi;
        }
        __syncthreads();
        if (tid < BM) {
            float bv = 3.402823466e38f; int bi = 0;
#pragma unroll
            for (int t = 0; t < TX; t++) {
                float v = rV[tid][t];
                if (v < bv) { bv = v; bi = rI[tid][t]; }
            }
            int gr = rowBase + tid;
            pVal[(size_t)gr * gridDim.x + blockIdx.x] = bv;
            pIdx[(size_t)gr * gridDim.x + blockIdx.x] = bi;
        }
    }
}

// ------------- per-row sum of squares (r6 bits) -----------------------------
__global__ void rowsumsq(const float* __restrict__ src, float* __restrict__ dst, int nRows) {
    int gw = (blockIdx.x * blockDim.x + threadIdx.x) >> 6;
    int lane = threadIdx.x & 63;
    if (gw >= nRows) return;
    const float4* s4 = reinterpret_cast<const float4*>(src + (size_t)gw * DIM);
    float4 a = s4[lane];
    float4 b = s4[lane + 64];
    float s = a.x * a.x + a.y * a.y + a.z * a.z + a.w * a.w
            + b.x * b.x + b.y * b.y + b.z * b.z + b.w * b.w;
#pragma unroll
    for (int o = 32; o; o >>= 1) s += __shfl_xor(s, o);
    if (lane == 0) dst[gw] = s;
}

// ------------- f32 -> f16 cast (8 elems / thread) ---------------------------
__global__ void cast_f16(const float* __restrict__ src, ushort* __restrict__ dst, int n8) {
    int t = blockIdx.x * blockDim.x + threadIdx.x;
    if (t >= n8) return;
    float4 a = reinterpret_cast<const float4*>(src)[(size_t)t * 2];
    float4 b = reinterpret_cast<const float4*>(src)[(size_t)t * 2 + 1];
    float v[8] = {a.x, a.y, a.z, a.w, b.x, b.y, b.z, b.w};
    ushort8 h;
#pragma unroll
    for (int e = 0; e < 8; ++e) {
        _Float16 hv = (_Float16)v[e];
        h[e] = *reinterpret_cast<unsigned short*>(&hv);
    }
    reinterpret_cast<ushort8*>(dst)[t] = h;
}

// ================= 256x256 8-phase MFMA f16 score GEMM (1-term) ==============
// r8-verified structure, unchanged.

#define NT_K 8
#define LDSOFF(BUF, ISB, KH) ((BUF) * 65536 + (ISB) * 32768 + (KH) * 16384)

__device__ __forceinline__ f16x8 read_frag(const char* half_base, int row, int g) {
    int gp = g ^ ((row >> 1) & 3);
    return *reinterpret_cast<const f16x8*>(half_base + row * 64 + gp * 16);
}

__device__ __forceinline__ void stage_half(const ushort* __restrict__ src, int rowBase,
                                           int segElem, char* ldsBase, int tid) {
#pragma unroll
    for (int i = 0; i < 2; ++i) {
        int o = i * 8192 + tid * 16;
        int row = o >> 6;
        int gp  = (o >> 4) & 3;
        int g   = gp ^ ((row >> 1) & 3);
        const char* gsrc = (const char*)src + (size_t)(rowBase + row) * 1024
                         + (size_t)segElem * 2 + g * 16;
        gload_lds16(gsrc, ldsBase + i * 8192 + (tid >> 6) * 1024);
    }
}

#define STAGE(STKT, STISB, STKH) do {                                          \
    int sk_ = (STKT) >= NT_K ? (STKT) - NT_K : (STKT);                         \
    int se_ = (sk_ << 6) + (STKH) * 32;                                        \
    const ushort* sp_ = (STISB) ? ch : xh;                                     \
    int rb_ = (STISB) ? colBase : rowBase;                                     \
    stage_half(sp_, rb_, se_, ldsc + LDSOFF((sk_ & 1), (STISB), (STKH)), tid); \
} while (0)

#define ENDP() do {                                                            \
    __builtin_amdgcn_s_barrier();                                              \
} while (0)
#define ENDV6() do {                                                           \
    asm volatile("s_waitcnt vmcnt(6)");                                        \
    __builtin_amdgcn_sched_barrier(0);                                         \
    __builtin_amdgcn_s_barrier();                                              \
} while (0)

#define PHASE_A(BUF, KS, STKT, STISB, STKH) do {                               \
    __builtin_amdgcn_sched_barrier(0);                                         \
    _Pragma("unroll")                                                          \
    for (int m_ = 0; m_ < 4; ++m_)                                             \
        af_[m_] = read_frag(ldsc + LDSOFF((BUF), 0, (KS)),                     \
                            wr * 128 + m_ * 16 + c15, g);                      \
    _Pragma("unroll")                                                          \
    for (int n_ = 0; n_ < 4; ++n_)                                             \
        bf_[n_] = read_frag(ldsc + LDSOFF((BUF), 1, (KS)),                     \
                            wc * 64 + n_ * 16 + c15, g);                       \
    STAGE((STKT), (STISB), (STKH));                                            \
    __builtin_amdgcn_sched_barrier(0);                                         \
    __builtin_amdgcn_s_barrier();                                              \
    asm volatile("s_waitcnt lgkmcnt(0)");                                      \
    __builtin_amdgcn_sched_barrier(0);                                         \
    __builtin_amdgcn_s_setprio(1);                                             \
    _Pragma("unroll")                                                          \
    for (int m_ = 0; m_ < 4; ++m_)                                             \
        _Pragma("unroll")                                                      \
        for (int n_ = 0; n_ < 4; ++n_)                                         \
            acc[m_][n_] = __builtin_amdgcn_mfma_f32_16x16x32_f16(              \
                af_[m_], bf_[n_], acc[m_][n_], 0, 0, 0);                       \
    __builtin_amdgcn_s_setprio(0);                                             \
    __builtin_amdgcn_sched_barrier(0);                                         \
} while (0)

#define PHASE_B(BUF, KS, STKT, STISB, STKH) do {                               \
    __builtin_amdgcn_sched_barrier(0);                                         \
    _Pragma("unroll")                                                          \
    for (int m_ = 0; m_ < 4; ++m_)                                             \
        af_[m_] = read_frag(ldsc + LDSOFF((BUF), 0, (KS)),                     \
                            wr * 128 + 64 + m_ * 16 + c15, g);                 \
    STAGE((STKT), (STISB), (STKH));                                            \
    __builtin_amdgcn_sched_barrier(0);                                         \
    __builtin_amdgcn_s_barrier();                                              \
    asm volatile("s_waitcnt lgkmcnt(0)");                                      \
    __builtin_amdgcn_sched_barrier(0);                                         \
    __builtin_amdgcn_s_setprio(1);                                             \
    _Pragma("unroll")                                                          \
    for (int m_ = 0; m_ < 4; ++m_)                                             \
        _Pragma("unroll")                                                      \
        for (int n_ = 0; n_ < 4; ++n_)                                         \
            acc[4 + m_][n_] = __builtin_amdgcn_mfma_f32_16x16x32_f16(          \
                af_[m_], bf_[n_], acc[4 + m_][n_], 0, 0, 0);                   \
    __builtin_amdgcn_s_setprio(0);                                             \
    __builtin_amdgcn_sched_barrier(0);                                         \
} while (0)

__launch_bounds__(512, 2)
__global__ void score_mfma8(const ushort* __restrict__ xh, const ushort* __restrict__ ch,
                            const float* __restrict__ xn2, const float* __restrict__ cn2,
                            float* __restrict__ pV1, float* __restrict__ pV2,
                            int* __restrict__ pI1) {
    __shared__ __align__(16) ushort LDSarr[65536];   // 128 KiB
    char* ldsc = (char*)LDSarr;

    int bid = blockIdx.x;                    // 512 blocks, 512 % 8 == 0
    int swz = (bid & 7) * 64 + (bid >> 3);   // XCD-aware
    int tileN = swz & 15;                    // 16 N tiles (4096/256)
    int tileM = swz >> 4;                    // 32 M tiles (8192/256)
    int rowBase = tileM * 256, colBase = tileN * 256;

    int tid = threadIdx.x, lane = tid & 63, w = tid >> 6;
    int wr = w >> 2, wc = w & 3;             // 2M x 4N wave grid
    int g = lane >> 4, c15 = lane & 15;

    f32x4 acc[8][4];
#pragma unroll
    for (int m = 0; m < 8; m++)
#pragma unroll
        for (int n = 0; n < 4; n++) acc[m][n] = (f32x4){0.f, 0.f, 0.f, 0.f};

    f16x8 af_[4], bf_[4];

    // prologue: T0 x4 + [B1.KH0, A1.KH0, B1.KH1] = 14 thread-instrs
    STAGE(0, 0, 0); STAGE(0, 1, 0); STAGE(0, 0, 1); STAGE(0, 1, 1);
    STAGE(1, 1, 0); STAGE(1, 0, 0); STAGE(1, 1, 1);
    __builtin_amdgcn_sched_barrier(0);
    asm volatile("s_waitcnt vmcnt(6)");      // T0 fully landed; 3 halves pending
    __builtin_amdgcn_sched_barrier(0);
    __builtin_amdgcn_s_barrier();

    for (int kt = 0; kt < NT_K; ++kt) {
        int buf = kt & 1;
        PHASE_A(buf, 0, kt + 1, 0, 1); ENDP();   // S1: A(kt+1).KH1
        PHASE_B(buf, 0, kt + 2, 1, 0); ENDP();   // S2: B(kt+2).KH0
        PHASE_A(buf, 1, kt + 2, 0, 0); ENDP();   // S3: A(kt+2).KH0
        PHASE_B(buf, 1, kt + 2, 1, 1); ENDV6();  // S4: B(kt+2).KH1 + vmcnt(6)
    }

    __syncthreads();   // full drain; LDS reused for reduction below

    // epilogue: score = xn2[row] + cn2[col] - 2*dot ; per-row (min1, idx1, min2)
    float* rv1 = (float*)ldsc;            // [256][4]
    float* rv2 = rv1 + 1024;              // [256][4]
    int*   ri1 = (int*)(rv1 + 2048);      // [256][4]

    float cnv[4];
#pragma unroll
    for (int n = 0; n < 4; ++n) cnv[n] = cn2[colBase + wc * 64 + n * 16 + c15];

#pragma unroll
    for (int m = 0; m < 8; ++m) {
#pragma unroll
        for (int j = 0; j < 4; ++j) {
            int rl = wr * 128 + m * 16 + g * 4 + j;
            float xn = xn2[rowBase + rl];
            float v1 = 3.402823466e38f, v2 = 3.402823466e38f; int i1 = 0x7fffffff;
#pragma unroll
            for (int n = 0; n < 4; ++n) {
                float s = xn + cnv[n] - 2.f * acc[m][n][j];
                int ci = colBase + wc * 64 + n * 16 + c15;
                if (s < v1 || (s == v1 && ci < i1)) { v2 = v1; v1 = s; i1 = ci; }
                else if (s < v2) v2 = s;
            }
#pragma unroll
            for (int off = 1; off < 16; off <<= 1) {
                float ov1 = __shfl_xor(v1, off);
                int   oi1 = __shfl_xor(i1, off);
                float ov2 = __shfl_xor(v2, off);
                if (ov1 < v1 || (ov1 == v1 && oi1 < i1)) {
                    v2 = fminf(v1, ov2); v1 = ov1; i1 = oi1;
                } else {
                    v2 = fminf(v2, ov1);
                }
            }
            if (c15 == 0) {
                rv1[rl * 4 + wc] = v1; rv2[rl * 4 + wc] = v2; ri1[rl * 4 + wc] = i1;
            }
        }
    }
    __syncthreads();
    if (tid < 256) {
        float v1 = 3.402823466e38f, v2 = 3.402823466e38f; int i1 = 0x7fffffff;
#pragma unroll
        for (int t = 0; t < 4; ++t) {
            float a1 = rv1[tid * 4 + t], a2 = rv2[tid * 4 + t];
            int   ai = ri1[tid * 4 + t];
            if (a1 < v1 || (a1 == v1 && ai < i1)) { v2 = fminf(v1, a2); v1 = a1; i1 = ai; }
            else { v2 = fminf(v2, a1); }
        }
        size_t o = (size_t)(rowBase + tid) * 16 + tileN;
        pV1[o] = v1; pV2[o] = v2; pI1[o] = i1;
    }
}

// ------------- combine per-tile partials -> idx + near-tie flag -------------
__global__ void combine_flag(const float* __restrict__ pV1, const float* __restrict__ pV2,
                             const int* __restrict__ pI1,
                             int* __restrict__ idx, float* __restrict__ idxF,
                             int* __restrict__ flag, float* __restrict__ vminOut) {
    int r = blockIdx.x * blockDim.x + threadIdx.x;
    if (r >= R_ROWS) return;
    float v1 = 3.402823466e38f, v2 = 3.402823466e38f; int i1 = 0x7fffffff;
    for (int t = 0; t < 16; ++t) {
        float a1 = pV1[(size_t)r * 16 + t];
        float a2 = pV2[(size_t)r * 16 + t];
        int   ai = pI1[(size_t)r * 16 + t];
        if (a1 < v1 || (a1 == v1 && ai < i1)) { v2 = fminf(v1, a2); v1 = a1; i1 = ai; }
        else { v2 = fminf(v2, a1); }
    }
    idx[r] = i1;
    idxF[r] = (float)i1;
    vminOut[r] = v1;
    flag[r] = (v2 - v1 < MARGIN) ? 1 : 0;
}

// ------------- exact f32 re-score, wave-cooperative coalesced ---------------
// One wave per candidate code: 64 lanes x float4 = contiguous 1KB reads.
// All-lane shuffle-reduced dot is identical across lanes; per-lane min
// tracking is therefore wave-uniform.
__launch_bounds__(256)
__global__ void refine_rows(const float* __restrict__ x, const float* __restrict__ cb,
                            const float* __restrict__ xn2, const float* __restrict__ cn2,
                            const float* __restrict__ pV1, const float* __restrict__ vmin,
                            const int* __restrict__ flag,
                            int* __restrict__ idx, float* __restrict__ idxF) {
    int r = blockIdx.x;
    if (flag[r] == 0) return;

    __shared__ float xs[DIM];
    __shared__ float wv[4];
    __shared__ int   wi[4];
    int tid = threadIdx.x, lane = tid & 63, w = tid >> 6;

    for (int i = tid; i < DIM; i += 256) xs[i] = x[(size_t)r * DIM + i];
    __syncthreads();

    float x0 = xs[lane * 4 + 0], x1 = xs[lane * 4 + 1];
    float x2 = xs[lane * 4 + 2], x3 = xs[lane * 4 + 3];
    float y0 = xs[256 + lane * 4 + 0], y1 = xs[256 + lane * 4 + 1];
    float y2 = xs[256 + lane * 4 + 2], y3 = xs[256 + lane * 4 + 3];

    float xn = xn2[r];
    float thr = vmin[r] + TILE_MARGIN;
    float v1 = 3.402823466e38f; int i1 = 0x7fffffff;

    for (int t = 0; t < 16; ++t) {
        if (pV1[(size_t)r * 16 + t] > thr) continue;
        for (int cc = w; cc < 256; cc += 4) {
            int c = t * 256 + cc;
            const float4* cr = reinterpret_cast<const float4*>(cb + (size_t)c * DIM);
            float4 a = cr[lane];
            float4 b = cr[lane + 64];
            float d = fmaf(x0, a.x, fmaf(x1, a.y, fmaf(x2, a.z, fmaf(x3, a.w,
                      fmaf(y0, b.x, fmaf(y1, b.y, fmaf(y2, b.z, y3 * b.w)))))));
#pragma unroll
            for (int o = 32; o; o >>= 1) d += __shfl_xor(d, o);
            float s = xn + cn2[c] - 2.f * d;
            if (s < v1 || (s == v1 && c < i1)) { v1 = s; i1 = c; }
        }
    }
    if (lane == 0) { wv[w] = v1; wi[w] = i1; }
    __syncthreads();
    if (tid == 0) {
        float bv = wv[0]; int bi = wi[0];
#pragma unroll
        for (int k = 1; k < 4; ++k) {
            if (wv[k] < bv || (wv[k] == bv && wi[k] < bi)) { bv = wv[k]; bi = wi[k]; }
        }
        idx[r] = bi; idxF[r] = (float)bi;
    }
}

// ------------- combine per-tile argmin partials (fallback path) -------------
__global__ void argmin_combine(const float* __restrict__ pVal, const int* __restrict__ pIdx,
                               int* __restrict__ idxOut, float* __restrict__ idxFloatOut,
                               int nTiles) {
    int r = blockIdx.x * blockDim.x + threadIdx.x;
    if (r >= R_ROWS) return;
    float bv = 3.402823466e38f; int bi = 0;
    for (int t = 0; t < nTiles; t++) {
        float v = pVal[(size_t)r * nTiles + t];
        if (v < bv) { bv = v; bi = pIdx[(size_t)r * nTiles + t]; }
    }
    idxOut[r] = bi;
    idxFloatOut[r] = (float)bi;
}

// ------------- rotation trick, one wave per row -----------------------------
__global__ void rotate_rows(const float* __restrict__ x, const float* __restrict__ cb,
                            const int* __restrict__ idx, float* __restrict__ out,
                            float* __restrict__ lossPartial) {
    int gw = (blockIdx.x * blockDim.x + threadIdx.x) >> 6;
    int lane = threadIdx.x & 63;
    if (gw >= R_ROWS) return;

    const float4* x4 = reinterpret_cast<const float4*>(x + (size_t)gw * DIM);
    float4 xa = x4[lane], xb = x4[lane + 64];
    int ci = idx[gw];
    const float4* q4 = reinterpret_cast<const float4*>(cb + (size_t)ci * DIM);
    float4 qa = q4[lane], qb = q4[lane + 64];

    float xe[8] = {xa.x, xa.y, xa.z, xa.w, xb.x, xb.y, xb.z, xb.w};
    float qe[8] = {qa.x, qa.y, qa.z, qa.w, qb.x, qb.y, qb.z, qb.w};

    auto wsum = [&](float v) {
#pragma unroll
        for (int o = 32; o; o >>= 1) v += __shfl_xor(v, o);
        return v;
    };

    float lx = 0.f, lq = 0.f, ld = 0.f;
#pragma unroll
    for (int e = 0; e < 8; e++) {
        lx += xe[e] * xe[e];
        lq += qe[e] * qe[e];
        float d = xe[e] - qe[e];
        ld += d * d;
    }
    float sx2 = wsum(lx);
    float sq2 = wsum(lq);
    float lp  = wsum(ld);

    float nx = sqrtf(sx2), nq = sqrtf(sq2);
    float inx = 1.f / fmaxf(nx, 1e-6f);
    float inq = 1.f / fmaxf(nq, 1e-6f);

    float ue[8], qh[8], we[8];
    float lw = 0.f;
#pragma unroll
    for (int e = 0; e < 8; e++) {
        ue[e] = xe[e] * inx;
        qh[e] = qe[e] * inq;
        we[e] = ue[e] + qh[e];
        lw += we[e] * we[e];
    }
    float sw2 = wsum(lw);
    float inw = 1.f / fmaxf(sqrtf(sw2), 1e-6f);

    float lew = 0.f, leu = 0.f;
#pragma unroll
    for (int e = 0; e < 8; e++) {
        we[e] *= inw;
        lew += xe[e] * we[e];
        leu += xe[e] * ue[e];
    }
    float ew = wsum(lew);
    float eu = wsum(leu);

    float scale = nq / fmaxf(nx, 1e-6f);
    float oe[8];
#pragma unroll
    for (int e = 0; e < 8; e++)
        oe[e] = (xe[e] - 2.f * ew * we[e] + 2.f * eu * qh[e]) * scale;

    float4* o4 = reinterpret_cast<float4*>(out + (size_t)gw * DIM);
    o4[lane]      = make_float4(oe[0], oe[1], oe[2], oe[3]);
    o4[lane + 64] = make_float4(oe[4], oe[5], oe[6], oe[7]);

    if (lane == 0) lossPartial[gw] = lp;
}

// ------------- final loss reduction -----------------------------------------
__global__ void loss_reduce(const float* __restrict__ lp, float* __restrict__ outScalar) {
    __shared__ float red[256];
    float s = 0.f;
    for (int i = threadIdx.x; i < R_ROWS; i += 256) s += lp[i];
    red[threadIdx.x] = s;
    __syncthreads();
    for (int o = 128; o; o >>= 1) {
        if (threadIdx.x < o) red[threadIdx.x] += red[threadIdx.x + o];
        __syncthreads();
    }
    if (threadIdx.x == 0)
        outScalar[0] = 1.25f * red[0] / (float)(R_ROWS * DIM);
}

extern "C" void kernel_launch(void* const* d_in, const int* in_sizes, int n_in,
                              void* d_out, int out_size, void* d_ws, size_t ws_size,
                              hipStream_t stream) {
    const float* x      = (const float*)d_in[0];   // [8192, 512]
    const float* frozen = (const float*)d_in[1];   // [4096, 512]
    const float* weight = (const float*)d_in[2];   // [512, 512]
    float* out = (float*)d_out;

    // ---- workspace layout (MFMA path), ~23 MB ----
    char* p = (char*)d_ws;
    float* cb  = (float*)p;            p += (size_t)NCODES * DIM * 4;
    ushort* xh = (ushort*)p;           p += (size_t)R_ROWS * DIM * 2;
    ushort* ch = (ushort*)p;           p += (size_t)NCODES * DIM * 2;
    float* cn2 = (float*)p;            p += NCODES * 4;
    float* xn2 = (float*)p;            p += R_ROWS * 4;
    float* pV1 = (float*)p;            p += (size_t)R_ROWS * 16 * 4;
    float* pV2 = (float*)p;            p += (size_t)R_ROWS * 16 * 4;
    int*   pI1 = (int*)p;              p += (size_t)R_ROWS * 16 * 4;
    int*   idx = (int*)p;              p += R_ROWS * 4;
    int*   flg = (int*)p;              p += R_ROWS * 4;
    float* vmn = (float*)p;            p += R_ROWS * 4;
    float* lp  = (float*)p;            p += R_ROWS * 4;
    size_t need = (size_t)(p - (char*)d_ws);

    if (ws_size >= need) {
        // 1. codebook = frozen @ W^T : f32 GEMM (round-6 bits)
        dim3 g1(DIM / 64, NCODES / 64);
        gemm_nt<64, 64, 4, 4, false><<<g1, 256, 0, stream>>>(
            frozen, weight, cb, nullptr, nullptr, nullptr, nullptr, NCODES, DIM, DIM);

        // 2. exact row norms (round-6 bits)
        rowsumsq<<<NCODES / 4, 256, 0, stream>>>(cb, cn2, NCODES);
        rowsumsq<<<R_ROWS / 4, 256, 0, stream>>>(x, xn2, R_ROWS);

        // 3. f16 casts
        cast_f16<<<(R_ROWS * DIM / 8) / 256, 256, 0, stream>>>(x, xh, R_ROWS * DIM / 8);
        cast_f16<<<(NCODES * DIM / 8) / 256, 256, 0, stream>>>(cb, ch, NCODES * DIM / 8);

        // 4. 1-term f16 MFMA score GEMM + per-tile (min1, idx1, min2)
        score_mfma8<<<(R_ROWS / 256) * (NCODES / 256), 512, 0, stream>>>(
            xh, ch, xn2, cn2, pV1, pV2, pI1);

        // 5. combine + near-tie flag
        combine_flag<<<R_ROWS / 256, 256, 0, stream>>>(
            pV1, pV2, pI1, idx, out + (size_t)R_ROWS * DIM, flg, vmn);

        // 6. exact f32 re-score of flagged rows (wave-coalesced)
        refine_rows<<<R_ROWS, 256, 0, stream>>>(
            x, cb, xn2, cn2, pV1, vmn, flg, idx, out + (size_t)R_ROWS * DIM);

        // 7. rotation trick + loss
        rotate_rows<<<R_ROWS / 4, 256, 0, stream>>>(x, cb, idx, out, lp);
        loss_reduce<<<1, 256, 0, stream>>>(lp, out + ((size_t)R_ROWS * DIM + R_ROWS));
    } else {
        // fallback: proven f32 path (~11 MB)
        float* fcn2 = (float*)((char*)d_ws + (size_t)NCODES * DIM * 4);
        float* fxn2 = fcn2 + NCODES;
        float* fpV = fxn2 + R_ROWS;
        int*   fpI = (int*)(fpV + (size_t)R_ROWS * 32);
        int*   fidx = (int*)(fpI + (size_t)R_ROWS * 32);
        float* flp = (float*)(fidx + R_ROWS);
        dim3 g1(DIM / 64, NCODES / 64);
        gemm_nt<64, 64, 4, 4, false><<<g1, 256, 0, stream>>>(
            frozen, weight, cb, nullptr, nullptr, nullptr, nullptr, NCODES, DIM, DIM);
        rowsumsq<<<NCODES / 4, 256, 0, stream>>>(cb, fcn2, NCODES);
        rowsumsq<<<R_ROWS / 4, 256, 0, stream>>>(x, fxn2, R_ROWS);
        dim3 g2(NCODES / 128, R_ROWS / 128);
        gemm_nt<128, 128, 8, 8, true><<<g2, 256, 0, stream>>>(
            x, cb, nullptr, fxn2, fcn2, fpV, fpI, R_ROWS, NCODES, DIM);
        argmin_combine<<<R_ROWS / 256, 256, 0, stream>>>(
            fpV, fpI, fidx, out + (size_t)R_ROWS * DIM, NCODES / 128);
        rotate_rows<<<R_ROWS / 4, 256, 0, stream>>>(x, cb, fidx, out, flp);
        loss_reduce<<<1, 256, 0, stream>>>(flp, out + ((size_t)R_ROWS * DIM + R_ROWS));
    }
}

// Round 10
// 217.161 us; speedup vs baseline: 1.9672x; 1.1926x over previous
//
#include <hip/hip_runtime.h>
#include <hip/hip_bf16.h>
#include <cstdint>

// SimVQ forward: b=8, n=1024 (R=8192 rows), dim=512, codes C=4096.
// Outputs flat f32: rotated [8192*512], indices-as-float [8192], loss [1].
//
// Round-10: r9 (PASSING) + 64-code-group refine granularity.
//   Score epilogue already computes per-(row, 64-code-group) (min1,min2,idx1);
//   store them as [64][8192] (group-major, coalesced). Refine builds a 64-bit
//   group pass-mask (ballot) and re-scores only passing groups, 4 waves x 16
//   codes each. Certificate: true-best code's group min <= vmin + 2*e_max
//   <= vmin + TILE_MARGIN (same bound as tile version).
// MARGIN/TILE_MARGIN, cb f32 GEMM, rowsumsq, f32 refine math: r9 bits.

#define R_ROWS 8192
#define DIM    512
#define NCODES 4096
#define BK     16
#define MARGIN      1.5e-2f
#define TILE_MARGIN 1.8e-2f

typedef __attribute__((ext_vector_type(8))) _Float16 f16x8;
typedef __attribute__((ext_vector_type(4))) float f32x4;
typedef __attribute__((ext_vector_type(8))) unsigned short ushort8;

__device__ __forceinline__ void gload_lds16(const void* g, void* l) {
    __builtin_amdgcn_global_load_lds(
        (const __attribute__((address_space(1))) void*)g,
        (__attribute__((address_space(3))) void*)l, 16, 0, 0);
}

// ---------------- generic f32 NT GEMM (cb + fallback) -----------------------
template<int BM, int BN, int TM, int TN, bool ARGMIN>
__launch_bounds__(256)
__global__ void gemm_nt(const float* __restrict__ A, const float* __restrict__ Bm,
                        float* __restrict__ Cout,
                        const float* __restrict__ rowAdd, const float* __restrict__ colAdd,
                        float* __restrict__ pVal, int* __restrict__ pIdx,
                        int M, int N, int K) {
    constexpr int THREADS = (BM / TM) * (BN / TN);
    constexpr int PAD = 4;
    __shared__ float As[BK][BM + PAD];
    __shared__ float Bs[BK][BN + PAD];

    const int tid = threadIdx.x;
    const int tx = tid % (BN / TN);
    const int ty = tid / (BN / TN);
    const int rowBase = blockIdx.y * BM;
    const int colBase = blockIdx.x * BN;

    float acc[TM][TN];
#pragma unroll
    for (int i = 0; i < TM; i++)
#pragma unroll
        for (int j = 0; j < TN; j++) acc[i][j] = 0.f;

    constexpr int A_F4 = BM * BK / 4;
    constexpr int B_F4 = BN * BK / 4;
    const int nK = K / BK;

    for (int kt = 0; kt < nK; ++kt) {
        const int k0 = kt * BK;
#pragma unroll
        for (int f = 0; f < A_F4 / THREADS; ++f) {
            int e = tid + f * THREADS;
            int row = e >> 2;
            int kq = e & 3;
            float4 v = *reinterpret_cast<const float4*>(
                &A[(size_t)(rowBase + row) * K + k0 + kq * 4]);
            As[kq * 4 + 0][row] = v.x; As[kq * 4 + 1][row] = v.y;
            As[kq * 4 + 2][row] = v.z; As[kq * 4 + 3][row] = v.w;
        }
#pragma unroll
        for (int f = 0; f < B_F4 / THREADS; ++f) {
            int e = tid + f * THREADS;
            int row = e >> 2;
            int kq = e & 3;
            float4 v = *reinterpret_cast<const float4*>(
                &Bm[(size_t)(colBase + row) * K + k0 + kq * 4]);
            Bs[kq * 4 + 0][row] = v.x; Bs[kq * 4 + 1][row] = v.y;
            Bs[kq * 4 + 2][row] = v.z; Bs[kq * 4 + 3][row] = v.w;
        }
        __syncthreads();

#pragma unroll
        for (int k = 0; k < BK; k++) {
            float a[TM], b[TN];
#pragma unroll
            for (int i4 = 0; i4 < TM / 4; i4++) {
                float4 v = *reinterpret_cast<const float4*>(&As[k][ty * TM + i4 * 4]);
                a[i4 * 4 + 0] = v.x; a[i4 * 4 + 1] = v.y;
                a[i4 * 4 + 2] = v.z; a[i4 * 4 + 3] = v.w;
            }
#pragma unroll
            for (int j4 = 0; j4 < TN / 4; j4++) {
                float4 v = *reinterpret_cast<const float4*>(&Bs[k][tx * TN + j4 * 4]);
                b[j4 * 4 + 0] = v.x; b[j4 * 4 + 1] = v.y;
                b[j4 * 4 + 2] = v.z; b[j4 * 4 + 3] = v.w;
            }
#pragma unroll
            for (int i = 0; i < TM; i++)
#pragma unroll
                for (int j = 0; j < TN; j++) acc[i][j] = fmaf(a[i], b[j], acc[i][j]);
        }
        __syncthreads();
    }

    if constexpr (!ARGMIN) {
#pragma unroll
        for (int i = 0; i < TM; i++) {
#pragma unroll
            for (int j4 = 0; j4 < TN / 4; j4++) {
                float4 v = make_float4(acc[i][j4 * 4 + 0], acc[i][j4 * 4 + 1],
                                       acc[i][j4 * 4 + 2], acc[i][j4 * 4 + 3]);
                *reinterpret_cast<float4*>(
                    &Cout[(size_t)(rowBase + ty * TM + i) * N + colBase + tx * TN + j4 * 4]) = v;
            }
        }
    } else {
        constexpr int TX = BN / TN;
        __shared__ float rV[BM][TX + 1];
        __shared__ int   rI[BM][TX + 1];
        float xn[TM];
#pragma unroll
        for (int i = 0; i < TM; i++) xn[i] = rowAdd[rowBase + ty * TM + i];
        float cn[TN];
#pragma unroll
        for (int j = 0; j < TN; j++) cn[j] = colAdd[colBase + tx * TN + j];

#pragma unroll
        for (int i = 0; i < TM; i++) {
            float bv = 3.402823466e38f; int bi = 0;
#pragma unroll
            for (int j = 0; j < TN; j++) {
                float s = xn[i] + cn[j] - 2.f * acc[i][j];
                if (s < bv) { bv = s; bi = colBase + tx * TN + j; }
            }
            rV[ty * TM + i][tx] = bv;
            rI[ty * TM + i][tx] = bi;
        }
        __syncthreads();
        if (tid < BM) {
            float bv = 3.402823466e38f; int bi = 0;
#pragma unroll
            for (int t = 0; t < TX; t++) {
                float v = rV[tid][t];
                if (v < bv) { bv = v; bi = rI[tid][t]; }
            }
            int gr = rowBase + tid;
            pVal[(size_t)gr * gridDim.x + blockIdx.x] = bv;
            pIdx[(size_t)gr * gridDim.x + blockIdx.x] = bi;
        }
    }
}

// ------------- per-row sum of squares (r6 bits) -----------------------------
__global__ void rowsumsq(const float* __restrict__ src, float* __restrict__ dst, int nRows) {
    int gw = (blockIdx.x * blockDim.x + threadIdx.x) >> 6;
    int lane = threadIdx.x & 63;
    if (gw >= nRows) return;
    const float4* s4 = reinterpret_cast<const float4*>(src + (size_t)gw * DIM);
    float4 a = s4[lane];
    float4 b = s4[lane + 64];
    float s = a.x * a.x + a.y * a.y + a.z * a.z + a.w * a.w
            + b.x * b.x + b.y * b.y + b.z * b.z + b.w * b.w;
#pragma unroll
    for (int o = 32; o; o >>= 1) s += __shfl_xor(s, o);
    if (lane == 0) dst[gw] = s;
}

// ------------- f32 -> f16 cast (8 elems / thread) ---------------------------
__global__ void cast_f16(const float* __restrict__ src, ushort* __restrict__ dst, int n8) {
    int t = blockIdx.x * blockDim.x + threadIdx.x;
    if (t >= n8) return;
    float4 a = reinterpret_cast<const float4*>(src)[(size_t)t * 2];
    float4 b = reinterpret_cast<const float4*>(src)[(size_t)t * 2 + 1];
    float v[8] = {a.x, a.y, a.z, a.w, b.x, b.y, b.z, b.w};
    ushort8 h;
#pragma unroll
    for (int e = 0; e < 8; ++e) {
        _Float16 hv = (_Float16)v[e];
        h[e] = *reinterpret_cast<unsigned short*>(&hv);
    }
    reinterpret_cast<ushort8*>(dst)[t] = h;
}

// ================= 256x256 8-phase MFMA f16 score GEMM (1-term) ==============
// r8/r9-verified structure. Epilogue now writes per-64-code-GROUP partials
// (min1,min2,idx1) to [64][8192] group-major arrays (no cross-group reduce).

#define NT_K 8
#define LDSOFF(BUF, ISB, KH) ((BUF) * 65536 + (ISB) * 32768 + (KH) * 16384)

__device__ __forceinline__ f16x8 read_frag(const char* half_base, int row, int g) {
    int gp = g ^ ((row >> 1) & 3);
    return *reinterpret_cast<const f16x8*>(half_base + row * 64 + gp * 16);
}

__device__ __forceinline__ void stage_half(const ushort* __restrict__ src, int rowBase,
                                           int segElem, char* ldsBase, int tid) {
#pragma unroll
    for (int i = 0; i < 2; ++i) {
        int o = i * 8192 + tid * 16;
        int row = o >> 6;
        int gp  = (o >> 4) & 3;
        int g   = gp ^ ((row >> 1) & 3);
        const char* gsrc = (const char*)src + (size_t)(rowBase + row) * 1024
                         + (size_t)segElem * 2 + g * 16;
        gload_lds16(gsrc, ldsBase + i * 8192 + (tid >> 6) * 1024);
    }
}

#define STAGE(STKT, STISB, STKH) do {                                          \
    int sk_ = (STKT) >= NT_K ? (STKT) - NT_K : (STKT);                         \
    int se_ = (sk_ << 6) + (STKH) * 32;                                        \
    const ushort* sp_ = (STISB) ? ch : xh;                                     \
    int rb_ = (STISB) ? colBase : rowBase;                                     \
    stage_half(sp_, rb_, se_, ldsc + LDSOFF((sk_ & 1), (STISB), (STKH)), tid); \
} while (0)

#define ENDP() do {                                                            \
    __builtin_amdgcn_s_barrier();                                              \
} while (0)
#define ENDV6() do {                                                           \
    asm volatile("s_waitcnt vmcnt(6)");                                        \
    __builtin_amdgcn_sched_barrier(0);                                         \
    __builtin_amdgcn_s_barrier();                                              \
} while (0)

#define PHASE_A(BUF, KS, STKT, STISB, STKH) do {                               \
    __builtin_amdgcn_sched_barrier(0);                                         \
    _Pragma("unroll")                                                          \
    for (int m_ = 0; m_ < 4; ++m_)                                             \
        af_[m_] = read_frag(ldsc + LDSOFF((BUF), 0, (KS)),                     \
                            wr * 128 + m_ * 16 + c15, g);                      \
    _Pragma("unroll")                                                          \
    for (int n_ = 0; n_ < 4; ++n_)                                             \
        bf_[n_] = read_frag(ldsc + LDSOFF((BUF), 1, (KS)),                     \
                            wc * 64 + n_ * 16 + c15, g);                       \
    STAGE((STKT), (STISB), (STKH));                                            \
    __builtin_amdgcn_sched_barrier(0);                                         \
    __builtin_amdgcn_s_barrier();                                              \
    asm volatile("s_waitcnt lgkmcnt(0)");                                      \
    __builtin_amdgcn_sched_barrier(0);                                         \
    __builtin_amdgcn_s_setprio(1);                                             \
    _Pragma("unroll")                                                          \
    for (int m_ = 0; m_ < 4; ++m_)                                             \
        _Pragma("unroll")                                                      \
        for (int n_ = 0; n_ < 4; ++n_)                                         \
            acc[m_][n_] = __builtin_amdgcn_mfma_f32_16x16x32_f16(              \
                af_[m_], bf_[n_], acc[m_][n_], 0, 0, 0);                       \
    __builtin_amdgcn_s_setprio(0);                                             \
    __builtin_amdgcn_sched_barrier(0);                                         \
} while (0)

#define PHASE_B(BUF, KS, STKT, STISB, STKH) do {                               \
    __builtin_amdgcn_sched_barrier(0);                                         \
    _Pragma("unroll")                                                          \
    for (int m_ = 0; m_ < 4; ++m_)                                             \
        af_[m_] = read_frag(ldsc + LDSOFF((BUF), 0, (KS)),                     \
                            wr * 128 + 64 + m_ * 16 + c15, g);                 \
    STAGE((STKT), (STISB), (STKH));                                            \
    __builtin_amdgcn_sched_barrier(0);                                         \
    __builtin_amdgcn_s_barrier();                                              \
    asm volatile("s_waitcnt lgkmcnt(0)");                                      \
    __builtin_amdgcn_sched_barrier(0);                                         \
    __builtin_amdgcn_s_setprio(1);                                             \
    _Pragma("unroll")                                                          \
    for (int m_ = 0; m_ < 4; ++m_)                                             \
        _Pragma("unroll")                                                      \
        for (int n_ = 0; n_ < 4; ++n_)                                         \
            acc[4 + m_][n_] = __builtin_amdgcn_mfma_f32_16x16x32_f16(          \
                af_[m_], bf_[n_], acc[4 + m_][n_], 0, 0, 0);                   \
    __builtin_amdgcn_s_setprio(0);                                             \
    __builtin_amdgcn_sched_barrier(0);                                         \
} while (0)

__launch_bounds__(512, 2)
__global__ void score_mfma8(const ushort* __restrict__ xh, const ushort* __restrict__ ch,
                            const float* __restrict__ xn2, const float* __restrict__ cn2,
                            float* __restrict__ pV1, float* __restrict__ pV2,
                            int* __restrict__ pI1) {
    __shared__ __align__(16) ushort LDSarr[65536];   // 128 KiB
    char* ldsc = (char*)LDSarr;

    int bid = blockIdx.x;                    // 512 blocks, 512 % 8 == 0
    int swz = (bid & 7) * 64 + (bid >> 3);   // XCD-aware
    int tileN = swz & 15;                    // 16 N tiles (4096/256)
    int tileM = swz >> 4;                    // 32 M tiles (8192/256)
    int rowBase = tileM * 256, colBase = tileN * 256;

    int tid = threadIdx.x, lane = tid & 63, w = tid >> 6;
    int wr = w >> 2, wc = w & 3;             // 2M x 4N wave grid
    int g = lane >> 4, c15 = lane & 15;

    f32x4 acc[8][4];
#pragma unroll
    for (int m = 0; m < 8; m++)
#pragma unroll
        for (int n = 0; n < 4; n++) acc[m][n] = (f32x4){0.f, 0.f, 0.f, 0.f};

    f16x8 af_[4], bf_[4];

    // prologue: T0 x4 + [B1.KH0, A1.KH0, B1.KH1] = 14 thread-instrs
    STAGE(0, 0, 0); STAGE(0, 1, 0); STAGE(0, 0, 1); STAGE(0, 1, 1);
    STAGE(1, 1, 0); STAGE(1, 0, 0); STAGE(1, 1, 1);
    __builtin_amdgcn_sched_barrier(0);
    asm volatile("s_waitcnt vmcnt(6)");      // T0 fully landed; 3 halves pending
    __builtin_amdgcn_sched_barrier(0);
    __builtin_amdgcn_s_barrier();

    for (int kt = 0; kt < NT_K; ++kt) {
        int buf = kt & 1;
        PHASE_A(buf, 0, kt + 1, 0, 1); ENDP();   // S1: A(kt+1).KH1
        PHASE_B(buf, 0, kt + 2, 1, 0); ENDP();   // S2: B(kt+2).KH0
        PHASE_A(buf, 1, kt + 2, 0, 0); ENDP();   // S3: A(kt+2).KH0
        PHASE_B(buf, 1, kt + 2, 1, 1); ENDV6();  // S4: B(kt+2).KH1 + vmcnt(6)
    }

    __syncthreads();   // full drain; LDS reused for staging below

    // epilogue: per-(row, 64-code-group) (min1, idx1, min2); group = tileN*4+wc
    float* rv1 = (float*)ldsc;            // [256][4]
    float* rv2 = rv1 + 1024;              // [256][4]
    int*   ri1 = (int*)(rv1 + 2048);      // [256][4]

    float cnv[4];
#pragma unroll
    for (int n = 0; n < 4; ++n) cnv[n] = cn2[colBase + wc * 64 + n * 16 + c15];

#pragma unroll
    for (int m = 0; m < 8; ++m) {
#pragma unroll
        for (int j = 0; j < 4; ++j) {
            int rl = wr * 128 + m * 16 + g * 4 + j;
            float xn = xn2[rowBase + rl];
            float v1 = 3.402823466e38f, v2 = 3.402823466e38f; int i1 = 0x7fffffff;
#pragma unroll
            for (int n = 0; n < 4; ++n) {
                float s = xn + cnv[n] - 2.f * acc[m][n][j];
                int ci = colBase + wc * 64 + n * 16 + c15;
                if (s < v1 || (s == v1 && ci < i1)) { v2 = v1; v1 = s; i1 = ci; }
                else if (s < v2) v2 = s;
            }
#pragma unroll
            for (int off = 1; off < 16; off <<= 1) {
                float ov1 = __shfl_xor(v1, off);
                int   oi1 = __shfl_xor(i1, off);
                float ov2 = __shfl_xor(v2, off);
                if (ov1 < v1 || (ov1 == v1 && oi1 < i1)) {
                    v2 = fminf(v1, ov2); v1 = ov1; i1 = oi1;
                } else {
                    v2 = fminf(v2, ov1);
                }
            }
            if (c15 == 0) {
                rv1[rl * 4 + wc] = v1; rv2[rl * 4 + wc] = v2; ri1[rl * 4 + wc] = i1;
            }
        }
    }
    __syncthreads();
    if (tid < 256) {
#pragma unroll
        for (int t = 0; t < 4; ++t) {
            size_t o = (size_t)(tileN * 4 + t) * R_ROWS + (rowBase + tid);
            pV1[o] = rv1[tid * 4 + t];
            pV2[o] = rv2[tid * 4 + t];
            pI1[o] = ri1[tid * 4 + t];
        }
    }
}

// ------------- combine per-group partials -> idx + near-tie flag ------------
// Group-major layout [64][8192]: thread r reads pV1[t*8192+r] — coalesced.
__global__ void combine_flag(const float* __restrict__ pV1, const float* __restrict__ pV2,
                             const int* __restrict__ pI1,
                             int* __restrict__ idx, float* __restrict__ idxF,
                             int* __restrict__ flag, float* __restrict__ vminOut) {
    int r = blockIdx.x * blockDim.x + threadIdx.x;
    if (r >= R_ROWS) return;
    float v1 = 3.402823466e38f, v2 = 3.402823466e38f; int i1 = 0x7fffffff;
    for (int t = 0; t < 64; ++t) {
        float a1 = pV1[(size_t)t * R_ROWS + r];
        float a2 = pV2[(size_t)t * R_ROWS + r];
        int   ai = pI1[(size_t)t * R_ROWS + r];
        if (a1 < v1 || (a1 == v1 && ai < i1)) { v2 = fminf(v1, a2); v1 = a1; i1 = ai; }
        else { v2 = fminf(v2, a1); }
    }
    idx[r] = i1;
    idxF[r] = (float)i1;
    vminOut[r] = v1;
    flag[r] = (v2 - v1 < MARGIN) ? 1 : 0;
}

// ------------- exact f32 re-score of flagged rows, group-filtered -----------
// Pass-mask over 64 groups built by wave 0 (ballot); per passing group all
// 4 waves cooperate (wave w takes codes cc = w, w+4, ...): 16 iters/wave.
__launch_bounds__(256)
__global__ void refine_rows(const float* __restrict__ x, const float* __restrict__ cb,
                            const float* __restrict__ xn2, const float* __restrict__ cn2,
                            const float* __restrict__ pV1, const float* __restrict__ vmin,
                            const int* __restrict__ flag,
                            int* __restrict__ idx, float* __restrict__ idxF) {
    int r = blockIdx.x;
    if (flag[r] == 0) return;

    __shared__ float xs[DIM];
    __shared__ float wv[4];
    __shared__ int   wi[4];
    __shared__ unsigned long long maskS;
    int tid = threadIdx.x, lane = tid & 63, w = tid >> 6;

    for (int i = tid; i < DIM; i += 256) xs[i] = x[(size_t)r * DIM + i];

    float thr = vmin[r] + TILE_MARGIN;
    if (tid < 64) {   // wave 0 exactly
        float gm = pV1[(size_t)tid * R_ROWS + r];
        unsigned long long b = __ballot(gm <= thr);
        if (tid == 0) maskS = b;
    }
    __syncthreads();

    float x0 = xs[lane * 4 + 0], x1 = xs[lane * 4 + 1];
    float x2 = xs[lane * 4 + 2], x3 = xs[lane * 4 + 3];
    float y0 = xs[256 + lane * 4 + 0], y1 = xs[256 + lane * 4 + 1];
    float y2 = xs[256 + lane * 4 + 2], y3 = xs[256 + lane * 4 + 3];

    float xn = xn2[r];
    float v1 = 3.402823466e38f; int i1 = 0x7fffffff;

    unsigned long long mask = maskS;
    while (mask) {
        int gq = __ffsll((long long)mask) - 1;
        mask &= mask - 1;
        for (int cc = w; cc < 64; cc += 4) {
            int c = gq * 64 + cc;
            const float4* cr = reinterpret_cast<const float4*>(cb + (size_t)c * DIM);
            float4 a = cr[lane];
            float4 b = cr[lane + 64];
            float d = fmaf(x0, a.x, fmaf(x1, a.y, fmaf(x2, a.z, fmaf(x3, a.w,
                      fmaf(y0, b.x, fmaf(y1, b.y, fmaf(y2, b.z, y3 * b.w)))))));
#pragma unroll
            for (int o = 32; o; o >>= 1) d += __shfl_xor(d, o);
            float s = xn + cn2[c] - 2.f * d;
            if (s < v1 || (s == v1 && c < i1)) { v1 = s; i1 = c; }
        }
    }
    if (lane == 0) { wv[w] = v1; wi[w] = i1; }
    __syncthreads();
    if (tid == 0) {
        float bv = wv[0]; int bi = wi[0];
#pragma unroll
        for (int k = 1; k < 4; ++k) {
            if (wv[k] < bv || (wv[k] == bv && wi[k] < bi)) { bv = wv[k]; bi = wi[k]; }
        }
        idx[r] = bi; idxF[r] = (float)bi;
    }
}

// ------------- combine per-tile argmin partials (fallback path) -------------
__global__ void argmin_combine(const float* __restrict__ pVal, const int* __restrict__ pIdx,
                               int* __restrict__ idxOut, float* __restrict__ idxFloatOut,
                               int nTiles) {
    int r = blockIdx.x * blockDim.x + threadIdx.x;
    if (r >= R_ROWS) return;
    float bv = 3.402823466e38f; int bi = 0;
    for (int t = 0; t < nTiles; t++) {
        float v = pVal[(size_t)r * nTiles + t];
        if (v < bv) { bv = v; bi = pIdx[(size_t)r * nTiles + t]; }
    }
    idxOut[r] = bi;
    idxFloatOut[r] = (float)bi;
}

// ------------- rotation trick, one wave per row -----------------------------
__global__ void rotate_rows(const float* __restrict__ x, const float* __restrict__ cb,
                            const int* __restrict__ idx, float* __restrict__ out,
                            float* __restrict__ lossPartial) {
    int gw = (blockIdx.x * blockDim.x + threadIdx.x) >> 6;
    int lane = threadIdx.x & 63;
    if (gw >= R_ROWS) return;

    const float4* x4 = reinterpret_cast<const float4*>(x + (size_t)gw * DIM);
    float4 xa = x4[lane], xb = x4[lane + 64];
    int ci = idx[gw];
    const float4* q4 = reinterpret_cast<const float4*>(cb + (size_t)ci * DIM);
    float4 qa = q4[lane], qb = q4[lane + 64];

    float xe[8] = {xa.x, xa.y, xa.z, xa.w, xb.x, xb.y, xb.z, xb.w};
    float qe[8] = {qa.x, qa.y, qa.z, qa.w, qb.x, qb.y, qb.z, qb.w};

    auto wsum = [&](float v) {
#pragma unroll
        for (int o = 32; o; o >>= 1) v += __shfl_xor(v, o);
        return v;
    };

    float lx = 0.f, lq = 0.f, ld = 0.f;
#pragma unroll
    for (int e = 0; e < 8; e++) {
        lx += xe[e] * xe[e];
        lq += qe[e] * qe[e];
        float d = xe[e] - qe[e];
        ld += d * d;
    }
    float sx2 = wsum(lx);
    float sq2 = wsum(lq);
    float lp  = wsum(ld);

    float nx = sqrtf(sx2), nq = sqrtf(sq2);
    float inx = 1.f / fmaxf(nx, 1e-6f);
    float inq = 1.f / fmaxf(nq, 1e-6f);

    float ue[8], qh[8], we[8];
    float lw = 0.f;
#pragma unroll
    for (int e = 0; e < 8; e++) {
        ue[e] = xe[e] * inx;
        qh[e] = qe[e] * inq;
        we[e] = ue[e] + qh[e];
        lw += we[e] * we[e];
    }
    float sw2 = wsum(lw);
    float inw = 1.f / fmaxf(sqrtf(sw2), 1e-6f);

    float lew = 0.f, leu = 0.f;
#pragma unroll
    for (int e = 0; e < 8; e++) {
        we[e] *= inw;
        lew += xe[e] * we[e];
        leu += xe[e] * ue[e];
    }
    float ew = wsum(lew);
    float eu = wsum(leu);

    float scale = nq / fmaxf(nx, 1e-6f);
    float oe[8];
#pragma unroll
    for (int e = 0; e < 8; e++)
        oe[e] = (xe[e] - 2.f * ew * we[e] + 2.f * eu * qh[e]) * scale;

    float4* o4 = reinterpret_cast<float4*>(out + (size_t)gw * DIM);
    o4[lane]      = make_float4(oe[0], oe[1], oe[2], oe[3]);
    o4[lane + 64] = make_float4(oe[4], oe[5], oe[6], oe[7]);

    if (lane == 0) lossPartial[gw] = lp;
}

// ------------- final loss reduction -----------------------------------------
__global__ void loss_reduce(const float* __restrict__ lp, float* __restrict__ outScalar) {
    __shared__ float red[256];
    float s = 0.f;
    for (int i = threadIdx.x; i < R_ROWS; i += 256) s += lp[i];
    red[threadIdx.x] = s;
    __syncthreads();
    for (int o = 128; o; o >>= 1) {
        if (threadIdx.x < o) red[threadIdx.x] += red[threadIdx.x + o];
        __syncthreads();
    }
    if (threadIdx.x == 0)
        outScalar[0] = 1.25f * red[0] / (float)(R_ROWS * DIM);
}

extern "C" void kernel_launch(void* const* d_in, const int* in_sizes, int n_in,
                              void* d_out, int out_size, void* d_ws, size_t ws_size,
                              hipStream_t stream) {
    const float* x      = (const float*)d_in[0];   // [8192, 512]
    const float* frozen = (const float*)d_in[1];   // [4096, 512]
    const float* weight = (const float*)d_in[2];   // [512, 512]
    float* out = (float*)d_out;

    // ---- workspace layout (MFMA path), ~29 MB ----
    char* p = (char*)d_ws;
    float* cb  = (float*)p;            p += (size_t)NCODES * DIM * 4;
    ushort* xh = (ushort*)p;           p += (size_t)R_ROWS * DIM * 2;
    ushort* ch = (ushort*)p;           p += (size_t)NCODES * DIM * 2;
    float* cn2 = (float*)p;            p += NCODES * 4;
    float* xn2 = (float*)p;            p += R_ROWS * 4;
    float* pV1 = (float*)p;            p += (size_t)R_ROWS * 64 * 4;   // [64][8192]
    float* pV2 = (float*)p;            p += (size_t)R_ROWS * 64 * 4;
    int*   pI1 = (int*)p;              p += (size_t)R_ROWS * 64 * 4;
    int*   idx = (int*)p;              p += R_ROWS * 4;
    int*   flg = (int*)p;              p += R_ROWS * 4;
    float* vmn = (float*)p;            p += R_ROWS * 4;
    float* lp  = (float*)p;            p += R_ROWS * 4;
    size_t need = (size_t)(p - (char*)d_ws);

    if (ws_size >= need) {
        // 1. codebook = frozen @ W^T : f32 GEMM (round-6 bits)
        dim3 g1(DIM / 64, NCODES / 64);
        gemm_nt<64, 64, 4, 4, false><<<g1, 256, 0, stream>>>(
            frozen, weight, cb, nullptr, nullptr, nullptr, nullptr, NCODES, DIM, DIM);

        // 2. exact row norms (round-6 bits)
        rowsumsq<<<NCODES / 4, 256, 0, stream>>>(cb, cn2, NCODES);
        rowsumsq<<<R_ROWS / 4, 256, 0, stream>>>(x, xn2, R_ROWS);

        // 3. f16 casts
        cast_f16<<<(R_ROWS * DIM / 8) / 256, 256, 0, stream>>>(x, xh, R_ROWS * DIM / 8);
        cast_f16<<<(NCODES * DIM / 8) / 256, 256, 0, stream>>>(cb, ch, NCODES * DIM / 8);

        // 4. 1-term f16 MFMA score GEMM + per-group (min1, idx1, min2)
        score_mfma8<<<(R_ROWS / 256) * (NCODES / 256), 512, 0, stream>>>(
            xh, ch, xn2, cn2, pV1, pV2, pI1);

        // 5. combine + near-tie flag
        combine_flag<<<R_ROWS / 256, 256, 0, stream>>>(
            pV1, pV2, pI1, idx, out + (size_t)R_ROWS * DIM, flg, vmn);

        // 6. exact f32 re-score of flagged rows (group-filtered, coalesced)
        refine_rows<<<R_ROWS, 256, 0, stream>>>(
            x, cb, xn2, cn2, pV1, vmn, flg, idx, out + (size_t)R_ROWS * DIM);

        // 7. rotation trick + loss
        rotate_rows<<<R_ROWS / 4, 256, 0, stream>>>(x, cb, idx, out, lp);
        loss_reduce<<<1, 256, 0, stream>>>(lp, out + ((size_t)R_ROWS * DIM + R_ROWS));
    } else {
        // fallback: proven f32 path (~11 MB)
        float* fcn2 = (float*)((char*)d_ws + (size_t)NCODES * DIM * 4);
        float* fxn2 = fcn2 + NCODES;
        float* fpV = fxn2 + R_ROWS;
        int*   fpI = (int*)(fpV + (size_t)R_ROWS * 32);
        int*   fidx = (int*)(fpI + (size_t)R_ROWS * 32);
        float* flp = (float*)(fidx + R_ROWS);
        dim3 g1(DIM / 64, NCODES / 64);
        gemm_nt<64, 64, 4, 4, false><<<g1, 256, 0, stream>>>(
            frozen, weight, cb, nullptr, nullptr, nullptr, nullptr, NCODES, DIM, DIM);
        rowsumsq<<<NCODES / 4, 256, 0, stream>>>(cb, fcn2, NCODES);
        rowsumsq<<<R_ROWS / 4, 256, 0, stream>>>(x, fxn2, R_ROWS);
        dim3 g2(NCODES / 128, R_ROWS / 128);
        gemm_nt<128, 128, 8, 8, true><<<g2, 256, 0, stream>>>(
            x, cb, nullptr, fxn2, fcn2, fpV, fpI, R_ROWS, NCODES, DIM);
        argmin_combine<<<R_ROWS / 256, 256, 0, stream>>>(
            fpV, fpI, fidx, out + (size_t)R_ROWS * DIM, NCODES / 128);
        rotate_rows<<<R_ROWS / 4, 256, 0, stream>>>(x, cb, fidx, out, flp);
        loss_reduce<<<1, 256, 0, stream>>>(flp, out + ((size_t)R_ROWS * DIM + R_ROWS));
    }
}